// Round 1
// baseline (809.046 us; speedup 1.0000x reference)
//
#include <hip/hip_runtime.h>
#include <math.h>

#define BB 8
#define TT 2048
#define DD 1024
#define HSZ 64

// ---------------------------------------------------------------------------
// QKV projection: one block computes 16 consecutive rows of Q, K, V.
// 192 threads: thread t -> matrix m = t>>6, column col = t&63.
// Context rows staged in LDS (64 KB) so the 768 KB of W traffic is amortized
// 16x across rows. W reads are coalesced (64 consecutive cols per wave).
// ---------------------------------------------------------------------------
__global__ __launch_bounds__(192) void qkv_proj_kernel(
    const float* __restrict__ ctx,
    const float* __restrict__ Wq, const float* __restrict__ Wk,
    const float* __restrict__ Wv,
    float* __restrict__ Q, float* __restrict__ K, float* __restrict__ V)
{
    constexpr int R = 16;
    __shared__ float cs[R][DD];  // 64 KB
    const int tid = threadIdx.x;
    const size_t row0 = (size_t)blockIdx.x * R;

    // cooperative load of 16 contiguous context rows (64 KB, float4 coalesced)
    const float4* src = (const float4*)(ctx + row0 * DD);
    float4* dst = (float4*)&cs[0][0];
    for (int i = tid; i < R * DD / 4; i += 192) dst[i] = src[i];
    __syncthreads();

    const int m = tid >> 6, col = tid & 63;
    const float* W  = (m == 0) ? Wq : (m == 1) ? Wk : Wv;
    float* outp     = (m == 0) ? Q  : (m == 1) ? K  : V;

    float acc[R];
    #pragma unroll
    for (int r = 0; r < R; ++r) acc[r] = 0.f;

    #pragma unroll 4
    for (int k = 0; k < DD; ++k) {
        float w = W[k * HSZ + col];       // coalesced across wave; L2-resident
        #pragma unroll
        for (int r = 0; r < R; ++r) acc[r] = fmaf(cs[r][k], w, acc[r]); // LDS broadcast
    }
    #pragma unroll
    for (int r = 0; r < R; ++r) outp[(row0 + r) * HSZ + col] = acc[r];
}

// ---------------------------------------------------------------------------
// Flash-style causal attention. One block per (batch, 64-query tile).
// 256 threads: thread t -> query row r = t>>2, subgroup sg = t&3.
//  - scores: thread computes S[r][s] for s = 4*i+sg (interleaved: bank-clean)
//  - online softmax: max/sum reduced across the 4 sg lanes via shfl_xor
//  - PV: thread accumulates O[r][d] for d in [16*sg, 16*sg+16)
// Ss row r is written and read only by lanes 4r..4r+3 (same wave) -> no
// extra __syncthreads needed for the P round-trip.
// ---------------------------------------------------------------------------
#define SQ 68   // LDS row stride: 64 + 4 pad, keeps float4 alignment, 2-way max aliasing

__device__ inline void fma4(float4& o, float p, const float4 v) {
    o.x = fmaf(p, v.x, o.x); o.y = fmaf(p, v.y, o.y);
    o.z = fmaf(p, v.z, o.z); o.w = fmaf(p, v.w, o.w);
}

__global__ __launch_bounds__(256) void attn_kernel(
    const float* __restrict__ Q, const float* __restrict__ K,
    const float* __restrict__ V, float* __restrict__ O)
{
    __shared__ float Ks[64][SQ];
    __shared__ float Vs[64][SQ];
    __shared__ float Ss[64][SQ];   // Q staging, then P matrix
    __shared__ float mrow[64], lrow[64];

    const int tid = threadIdx.x;
    const int qt = blockIdx.x, b = blockIdx.y;
    const int r = tid >> 2, sg = tid & 3;
    const int d0 = sg * 16;
    const size_t bofs = (size_t)b * TT * HSZ;

    // stage Q tile into Ss
    {
        const float4* src = (const float4*)(Q + bofs + (size_t)qt * 64 * HSZ);
        for (int i = tid; i < 64 * HSZ / 4; i += 256) {
            int rr = i >> 4, c4 = i & 15;
            *(float4*)&Ss[rr][c4 * 4] = src[i];
        }
    }
    if (tid < 64) { mrow[tid] = -INFINITY; lrow[tid] = 0.f; }
    __syncthreads();

    // Q row -> registers (constant across all key tiles)
    float4 qreg[16];
    #pragma unroll
    for (int j = 0; j < 16; ++j) qreg[j] = *(const float4*)&Ss[r][j * 4];

    float4 o0 = {0,0,0,0}, o1 = {0,0,0,0}, o2 = {0,0,0,0}, o3 = {0,0,0,0};
    const float scale = 0.125f;  // HS^-0.5

    for (int kt = 0; kt <= qt; ++kt) {
        __syncthreads();  // prev tile's compute done (and qreg reads on iter 0)

        // load K,V tiles
        const float4* Kb = (const float4*)(K + bofs + (size_t)kt * 64 * HSZ);
        const float4* Vb = (const float4*)(V + bofs + (size_t)kt * 64 * HSZ);
        for (int i = tid; i < 64 * HSZ / 4; i += 256) {
            int rr = i >> 4, c4 = i & 15;
            *(float4*)&Ks[rr][c4 * 4] = Kb[i];
            *(float4*)&Vs[rr][c4 * 4] = Vb[i];
        }
        __syncthreads();

        // ---- scores S[r][s], s = 4i+sg ----
        const bool diag = (kt == qt);
        float sc[16];
        #pragma unroll 4
        for (int i = 0; i < 16; ++i) {
            int s = (i << 2) | sg;
            const float4* krow = (const float4*)&Ks[s][0];
            float acc = 0.f;
            #pragma unroll
            for (int j = 0; j < 16; ++j) {
                float4 a = qreg[j], k4 = krow[j];
                acc = fmaf(a.x, k4.x, acc); acc = fmaf(a.y, k4.y, acc);
                acc = fmaf(a.z, k4.z, acc); acc = fmaf(a.w, k4.w, acc);
            }
            acc *= scale;
            if (diag && s > r) acc = -INFINITY;
            sc[i] = acc;
        }

        // ---- online softmax (4-lane reduce) ----
        float mx = sc[0];
        #pragma unroll
        for (int i = 1; i < 16; ++i) mx = fmaxf(mx, sc[i]);
        mx = fmaxf(mx, __shfl_xor(mx, 1));
        mx = fmaxf(mx, __shfl_xor(mx, 2));

        float m_old = mrow[r];
        float m_new = fmaxf(m_old, mx);
        float ls = 0.f;
        #pragma unroll
        for (int i = 0; i < 16; ++i) {
            int s = (i << 2) | sg;
            float p = __expf(sc[i] - m_new);
            ls += p;
            Ss[r][s] = p;
        }
        ls += __shfl_xor(ls, 1);
        ls += __shfl_xor(ls, 2);
        float alpha = __expf(m_old - m_new);
        if (sg == 0) { mrow[r] = m_new; lrow[r] = lrow[r] * alpha + ls; }

        o0.x *= alpha; o0.y *= alpha; o0.z *= alpha; o0.w *= alpha;
        o1.x *= alpha; o1.y *= alpha; o1.z *= alpha; o1.w *= alpha;
        o2.x *= alpha; o2.y *= alpha; o2.z *= alpha; o2.w *= alpha;
        o3.x *= alpha; o3.y *= alpha; o3.z *= alpha; o3.w *= alpha;

        // ---- O[r][d0..d0+15] += sum_s P[r][s] * V[s][d] ----
        #pragma unroll 8
        for (int s = 0; s < 64; ++s) {
            float p = Ss[r][s];                          // same-wave producer
            const float4* vrow = (const float4*)&Vs[s][d0];
            fma4(o0, p, vrow[0]); fma4(o1, p, vrow[1]);
            fma4(o2, p, vrow[2]); fma4(o3, p, vrow[3]);
        }
    }

    float linv = 1.f / lrow[r];   // written by lane 4r, same wave
    o0.x *= linv; o0.y *= linv; o0.z *= linv; o0.w *= linv;
    o1.x *= linv; o1.y *= linv; o1.z *= linv; o1.w *= linv;
    o2.x *= linv; o2.y *= linv; o2.z *= linv; o2.w *= linv;
    o3.x *= linv; o3.y *= linv; o3.z *= linv; o3.w *= linv;

    float4* Ob = (float4*)(O + bofs + (size_t)(qt * 64 + r) * HSZ + d0);
    Ob[0] = o0; Ob[1] = o1; Ob[2] = o2; Ob[3] = o3;
}

// ---------------------------------------------------------------------------
extern "C" void kernel_launch(void* const* d_in, const int* in_sizes, int n_in,
                              void* d_out, int out_size, void* d_ws, size_t ws_size,
                              hipStream_t stream) {
    const float* ctx = (const float*)d_in[0];
    const float* Wq  = (const float*)d_in[1];
    const float* Wk  = (const float*)d_in[2];
    const float* Wv  = (const float*)d_in[3];
    float* out = (float*)d_out;

    const size_t NQ = (size_t)BB * TT * HSZ;   // 1,048,576 floats per tensor
    float* Qw = (float*)d_ws;
    float* Kw = Qw + NQ;
    float* Vw = Kw + NQ;

    qkv_proj_kernel<<<BB * TT / 16, 192, 0, stream>>>(ctx, Wq, Wk, Wv, Qw, Kw, Vw);
    attn_kernel<<<dim3(TT / 64, BB), 256, 0, stream>>>(Qw, Kw, Vw, out);
}

// Round 2
// 244.513 us; speedup vs baseline: 3.3088x; 3.3088x over previous
//
#include <hip/hip_runtime.h>
#include <math.h>

#define BB 8
#define TT 2048
#define DD 1024
#define HSZ 64

typedef __bf16 bf16_t;
typedef bf16_t bf16x8 __attribute__((ext_vector_type(8)));
typedef float f32x4 __attribute__((ext_vector_type(4)));

#define MFMA16(A, B, C) __builtin_amdgcn_mfma_f32_16x16x32_bf16(A, B, C, 0, 0, 0)

// ---------------------------------------------------------------------------
// Wt[m][n][k] = W_m[k][n] as bf16.  [3][64][1024]
// ---------------------------------------------------------------------------
__global__ __launch_bounds__(256) void wt_convert(
    const float* __restrict__ Wq, const float* __restrict__ Wk,
    const float* __restrict__ Wv, bf16_t* __restrict__ Wt)
{
    int id = blockIdx.x * 256 + threadIdx.x;      // 0 .. 196607
    int k = id & 1023;
    int n = (id >> 10) & 63;
    int m = id >> 16;
    const float* W = (m == 0) ? Wq : (m == 1) ? Wk : Wv;
    Wt[id] = (bf16_t)W[k * HSZ + n];
}

// ---------------------------------------------------------------------------
// QKV projection, MFMA bf16.  Block: 64 context rows, 256 threads = 4 waves.
// Wave w owns rows w*16..w*16+15; computes all 192 output cols (12 C-tiles).
// A (ctx) staged+converted in LDS per 64-k chunk; B (Wt) read from global/L2.
// ---------------------------------------------------------------------------
__global__ __launch_bounds__(256) void qkv_proj(
    const float* __restrict__ ctx, const bf16_t* __restrict__ Wt,
    bf16_t* __restrict__ Q, bf16_t* __restrict__ K, bf16_t* __restrict__ V)
{
    __shared__ bf16_t As[64][72];   // stride 72 bf16 = 144 B (16B-aligned rows)

    const int tid = threadIdx.x;
    const int w = tid >> 6, lane = tid & 63;
    const int quad = lane >> 4, l16 = lane & 15;
    const size_t row0 = (size_t)blockIdx.x * 64;

    f32x4 acc[12];
    #pragma unroll
    for (int i = 0; i < 12; ++i) acc[i] = (f32x4){0.f, 0.f, 0.f, 0.f};

    const int srow = tid >> 2, sseg = tid & 3;   // staging: 4 threads/row

    for (int kc = 0; kc < DD; kc += 64) {
        __syncthreads();
        {   // stage 64x64 fp32 -> bf16 LDS
            const float4* src = (const float4*)(ctx + (row0 + srow) * DD + kc) + sseg * 4;
            float4 a0 = src[0], a1 = src[1], a2 = src[2], a3 = src[3];
            bf16x8 lo, hi;
            lo[0]=(bf16_t)a0.x; lo[1]=(bf16_t)a0.y; lo[2]=(bf16_t)a0.z; lo[3]=(bf16_t)a0.w;
            lo[4]=(bf16_t)a1.x; lo[5]=(bf16_t)a1.y; lo[6]=(bf16_t)a1.z; lo[7]=(bf16_t)a1.w;
            hi[0]=(bf16_t)a2.x; hi[1]=(bf16_t)a2.y; hi[2]=(bf16_t)a2.z; hi[3]=(bf16_t)a2.w;
            hi[4]=(bf16_t)a3.x; hi[5]=(bf16_t)a3.y; hi[6]=(bf16_t)a3.z; hi[7]=(bf16_t)a3.w;
            *(bf16x8*)&As[srow][sseg * 16]     = lo;
            *(bf16x8*)&As[srow][sseg * 16 + 8] = hi;
        }
        __syncthreads();

        #pragma unroll
        for (int ks = 0; ks < 2; ++ks) {
            bf16x8 afrag = *(const bf16x8*)&As[w * 16 + l16][ks * 32 + quad * 8];
            #pragma unroll
            for (int nt = 0; nt < 12; ++nt) {
                const bf16_t* wp = Wt + ((size_t)(nt >> 2) * 64 + (nt & 3) * 16 + l16) * DD
                                      + kc + ks * 32 + quad * 8;
                bf16x8 bfrag = *(const bf16x8*)wp;
                acc[nt] = MFMA16(afrag, bfrag, acc[nt]);
            }
        }
    }

    // epilogue: C-layout row = quad*4+reg, col = l16 (within 16-col tile)
    #pragma unroll
    for (int nt = 0; nt < 12; ++nt) {
        int m = nt >> 2;
        bf16_t* outp = (m == 0) ? Q : (m == 1) ? K : V;
        int col = (nt & 3) * 16 + l16;
        #pragma unroll
        for (int reg = 0; reg < 4; ++reg) {
            size_t t = row0 + w * 16 + quad * 4 + reg;
            outp[t * HSZ + col] = (bf16_t)acc[nt][reg];
        }
    }
}

// ---------------------------------------------------------------------------
// Flash MFMA attention.  Block = (b, 64-query tile), 256 threads = 4 waves,
// wave w owns q rows w*16..w*16+15.  K-tile = 64 keys per iteration.
//  S = Q K^T  via mfma 16x16x32 (A=Q frags in reg, B=K from LDS row-major)
//  online softmax per 16-lane group (shfl_xor 1/2/4/8)
//  P: C-layout -> LDS (per-wave region) -> A-layout frags
//  O += P V    via mfma (B = V transposed in LDS: Vts[d][key])
// ---------------------------------------------------------------------------
__global__ __launch_bounds__(256) void attn_kernel(
    const bf16_t* __restrict__ Q, const bf16_t* __restrict__ K,
    const bf16_t* __restrict__ V, float* __restrict__ O)
{
    __shared__ bf16_t Ks[64][72];
    __shared__ bf16_t Vts[64][72];     // [d][key]
    __shared__ bf16_t Ps[4][16][72];   // per-wave P strips

    const int tid = threadIdx.x;
    const int w = tid >> 6, lane = tid & 63;
    const int quad = lane >> 4, l16 = lane & 15;
    const int qt = blockIdx.x, b = blockIdx.y;
    const size_t base = (size_t)b * TT * HSZ;

    // Q A-frags in registers for the whole kernel
    const bf16_t* qp = Q + base + (size_t)(qt * 64 + w * 16 + l16) * HSZ + quad * 8;
    bf16x8 qf0 = *(const bf16x8*)qp;
    bf16x8 qf1 = *(const bf16x8*)(qp + 32);

    f32x4 o[4];
    #pragma unroll
    for (int dt = 0; dt < 4; ++dt) o[dt] = (f32x4){0.f, 0.f, 0.f, 0.f};
    float m_run[4], l_run[4];
    #pragma unroll
    for (int r = 0; r < 4; ++r) { m_run[r] = -INFINITY; l_run[r] = 0.f; }

    const int vkey = tid >> 2, vdg = tid & 3;    // V-transpose staging roles

    for (int kt = 0; kt <= qt; ++kt) {
        __syncthreads();
        {   // stage K row-major (512 x 16B chunks)
            const uint4* Kg = (const uint4*)(K + base + (size_t)kt * 64 * HSZ);
            uint4 x0 = Kg[tid], x1 = Kg[tid + 256];
            *(uint4*)&Ks[tid >> 3][(tid & 7) * 8] = x0;
            *(uint4*)&Ks[(tid + 256) >> 3][(tid & 7) * 8] = x1;
            // stage V transposed: thread reads V[key][vdg*16..+16], scatters to Vts
            const bf16_t* vrow = V + base + (size_t)(kt * 64 + vkey) * HSZ + vdg * 16;
            bf16x8 v0 = *(const bf16x8*)vrow;
            bf16x8 v1 = *(const bf16x8*)(vrow + 8);
            #pragma unroll
            for (int j = 0; j < 8; ++j) Vts[vdg * 16 + j][vkey] = v0[j];
            #pragma unroll
            for (int j = 0; j < 8; ++j) Vts[vdg * 16 + 8 + j][vkey] = v1[j];
        }
        __syncthreads();

        const bool diag = (kt == qt);
        const int nv = diag ? (w + 1) : 4;

        // ---- S = Q K^T ----
        f32x4 sc[4];
        for (int n = 0; n < nv; ++n) {
            bf16x8 kf0 = *(const bf16x8*)&Ks[n * 16 + l16][quad * 8];
            bf16x8 kf1 = *(const bf16x8*)&Ks[n * 16 + l16][32 + quad * 8];
            f32x4 a = (f32x4){0.f, 0.f, 0.f, 0.f};
            a = MFMA16(qf0, kf0, a);
            a = MFMA16(qf1, kf1, a);
            sc[n] = a;
        }

        // ---- scale + causal mask + row max ----
        float mx[4];
        #pragma unroll
        for (int r = 0; r < 4; ++r) mx[r] = -INFINITY;
        for (int n = 0; n < nv; ++n) {
            #pragma unroll
            for (int reg = 0; reg < 4; ++reg) {
                float s = sc[n][reg] * 0.125f;
                if (diag && n == w && l16 > quad * 4 + reg) s = -INFINITY;
                sc[n][reg] = s;
                mx[reg] = fmaxf(mx[reg], s);
            }
        }
        #pragma unroll
        for (int reg = 0; reg < 4; ++reg) {
            float v = mx[reg];
            v = fmaxf(v, __shfl_xor(v, 1)); v = fmaxf(v, __shfl_xor(v, 2));
            v = fmaxf(v, __shfl_xor(v, 4)); v = fmaxf(v, __shfl_xor(v, 8));
            mx[reg] = v;
        }

        // ---- online softmax update ----
        float alpha[4], ls[4];
        #pragma unroll
        for (int reg = 0; reg < 4; ++reg) {
            float m_new = fmaxf(m_run[reg], mx[reg]);
            alpha[reg] = __expf(m_run[reg] - m_new);
            m_run[reg] = m_new;
            ls[reg] = 0.f;
        }
        for (int n = 0; n < nv; ++n) {
            #pragma unroll
            for (int reg = 0; reg < 4; ++reg) {
                float p = __expf(sc[n][reg] - m_run[reg]);
                sc[n][reg] = p;
                ls[reg] += p;
            }
        }
        #pragma unroll
        for (int reg = 0; reg < 4; ++reg) {
            float v = ls[reg];
            v += __shfl_xor(v, 1); v += __shfl_xor(v, 2);
            v += __shfl_xor(v, 4); v += __shfl_xor(v, 8);
            l_run[reg] = l_run[reg] * alpha[reg] + v;
        }
        #pragma unroll
        for (int dt = 0; dt < 4; ++dt) {
            #pragma unroll
            for (int reg = 0; reg < 4; ++reg) o[dt][reg] *= alpha[reg];
        }

        // ---- P: C-layout -> LDS (bf16), zero-fill skipped subtiles ----
        #pragma unroll
        for (int n = 0; n < 4; ++n) {
            #pragma unroll
            for (int reg = 0; reg < 4; ++reg) {
                float p = (n < nv) ? sc[n][reg] : 0.f;
                Ps[w][quad * 4 + reg][n * 16 + l16] = (bf16_t)p;
            }
        }
        // A-layout frags (same-wave region; DS ops in order within wave)
        bf16x8 pf0 = *(const bf16x8*)&Ps[w][l16][quad * 8];
        bf16x8 pf1 = *(const bf16x8*)&Ps[w][l16][32 + quad * 8];

        // ---- O += P V ----
        #pragma unroll
        for (int dt = 0; dt < 4; ++dt) {
            bf16x8 vf0 = *(const bf16x8*)&Vts[dt * 16 + l16][quad * 8];
            bf16x8 vf1 = *(const bf16x8*)&Vts[dt * 16 + l16][32 + quad * 8];
            o[dt] = MFMA16(pf0, vf0, o[dt]);
            o[dt] = MFMA16(pf1, vf1, o[dt]);
        }
    }

    // ---- epilogue: normalize and store fp32 ----
    float linv[4];
    #pragma unroll
    for (int reg = 0; reg < 4; ++reg) linv[reg] = 1.f / l_run[reg];
    #pragma unroll
    for (int dt = 0; dt < 4; ++dt) {
        #pragma unroll
        for (int reg = 0; reg < 4; ++reg) {
            size_t t = (size_t)(qt * 64 + w * 16 + quad * 4 + reg);
            O[base + t * HSZ + dt * 16 + l16] = o[dt][reg] * linv[reg];
        }
    }
}

// ---------------------------------------------------------------------------
extern "C" void kernel_launch(void* const* d_in, const int* in_sizes, int n_in,
                              void* d_out, int out_size, void* d_ws, size_t ws_size,
                              hipStream_t stream) {
    const float* ctx = (const float*)d_in[0];
    const float* Wq  = (const float*)d_in[1];
    const float* Wk  = (const float*)d_in[2];
    const float* Wv  = (const float*)d_in[3];
    float* out = (float*)d_out;

    const size_t NQ = (size_t)BB * TT * HSZ;   // 1,048,576
    bf16_t* Qw = (bf16_t*)d_ws;
    bf16_t* Kw = Qw + NQ;
    bf16_t* Vw = Kw + NQ;
    bf16_t* Wt = Vw + NQ;                      // [3][64][1024]

    wt_convert<<<768, 256, 0, stream>>>(Wq, Wk, Wv, Wt);
    qkv_proj<<<BB * TT / 64, 256, 0, stream>>>(ctx, Wt, Qw, Kw, Vw);
    attn_kernel<<<dim3(TT / 64, BB), 256, 0, stream>>>(Qw, Kw, Vw, out);
}

// Round 3
// 214.785 us; speedup vs baseline: 3.7668x; 1.1384x over previous
//
#include <hip/hip_runtime.h>
#include <math.h>

#define BB 8
#define TT 2048
#define DD 1024
#define HSZ 64

typedef __bf16 bf16_t;
typedef bf16_t bf16x8 __attribute__((ext_vector_type(8)));
typedef bf16_t bf16x4 __attribute__((ext_vector_type(4)));
typedef float f32x4 __attribute__((ext_vector_type(4)));

#define MFMA16(A, B, C) __builtin_amdgcn_mfma_f32_16x16x32_bf16(A, B, C, 0, 0, 0)

// ---------------------------------------------------------------------------
// Wt[m][n][k] = W_m[k][n] as bf16.  [3][64][1024]
// ---------------------------------------------------------------------------
__global__ __launch_bounds__(256) void wt_convert(
    const float* __restrict__ Wq, const float* __restrict__ Wk,
    const float* __restrict__ Wv, bf16_t* __restrict__ Wt)
{
    int id = blockIdx.x * 256 + threadIdx.x;      // 0 .. 196607
    int k = id & 1023;
    int n = (id >> 10) & 63;
    int m = id >> 16;
    const float* W = (m == 0) ? Wq : (m == 1) ? Wk : Wv;
    Wt[id] = (bf16_t)W[k * HSZ + n];
}

// ---------------------------------------------------------------------------
// QKV projection, barrier-free.  1024 independent waves (256 blocks x 4).
// Wave: 16 ctx rows x all 192 output cols.  A-frags straight from global fp32
// (converted in reg), B-frags from Wt (L2-resident).  No LDS, no syncs.
// Q,K written row-major bf16; V written TRANSPOSED: Vt[b][d][t] (the C-layout
// epilogue has 4 consecutive t per lane -> packed 8B stores).
// ---------------------------------------------------------------------------
__global__ __launch_bounds__(256) void qkv_proj(
    const float* __restrict__ ctx, const bf16_t* __restrict__ Wt,
    bf16_t* __restrict__ Q, bf16_t* __restrict__ K, bf16_t* __restrict__ Vt)
{
    const int tid = threadIdx.x;
    const int w = tid >> 6, lane = tid & 63;
    const int quad = lane >> 4, l16 = lane & 15;
    const int gw = blockIdx.x * 4 + w;            // 0..1023
    const size_t row0 = (size_t)gw * 16;          // composite row b*2048 + t

    f32x4 acc[12];
    #pragma unroll
    for (int i = 0; i < 12; ++i) acc[i] = (f32x4){0.f, 0.f, 0.f, 0.f};

    const float* arow = ctx + (row0 + l16) * DD + quad * 8;

    #pragma unroll 2
    for (int kc = 0; kc < DD; kc += 32) {
        float4 a0 = *(const float4*)(arow + kc);
        float4 a1 = *(const float4*)(arow + kc + 4);
        bf16x8 af;
        af[0] = (bf16_t)a0.x; af[1] = (bf16_t)a0.y;
        af[2] = (bf16_t)a0.z; af[3] = (bf16_t)a0.w;
        af[4] = (bf16_t)a1.x; af[5] = (bf16_t)a1.y;
        af[6] = (bf16_t)a1.z; af[7] = (bf16_t)a1.w;
        #pragma unroll
        for (int nt = 0; nt < 12; ++nt) {
            const bf16_t* wp = Wt + ((size_t)(nt >> 2) * 64 + (nt & 3) * 16 + l16) * DD
                                  + kc + quad * 8;
            bf16x8 bfrag = *(const bf16x8*)wp;
            acc[nt] = MFMA16(af, bfrag, acc[nt]);
        }
    }

    // Q, K: row-major scalar stores (C-layout: row=quad*4+reg, col=l16)
    #pragma unroll
    for (int nt = 0; nt < 8; ++nt) {
        bf16_t* outp = (nt < 4) ? Q : K;
        int col = (nt & 3) * 16 + l16;
        #pragma unroll
        for (int reg = 0; reg < 4; ++reg)
            outp[(row0 + quad * 4 + reg) * HSZ + col] = (bf16_t)acc[nt][reg];
    }
    // V: transposed Vt[b][d][t], 4 consecutive t -> one 8B store
    const int bb = gw >> 7;
    const int t0 = (int)(row0 & 2047) + quad * 4;
    #pragma unroll
    for (int nt = 8; nt < 12; ++nt) {
        int d = (nt & 3) * 16 + l16;
        bf16x4 v;
        #pragma unroll
        for (int reg = 0; reg < 4; ++reg) v[reg] = (bf16_t)acc[nt][reg];
        *(bf16x4*)(Vt + ((size_t)bb * 64 + d) * TT + t0) = v;
    }
}

// ---------------------------------------------------------------------------
// Barrier-free flash attention.  1024 single-wave blocks; block -> 16-row
// q-strip (b, j).  Mapping keeps per-CU strip sums constant (j-sums = 254)
// and dispatches long strips first.  K frags double-buffered in registers;
// Vt frags loaded early in the tile body; only LDS use is the per-wave
// 16x64 P C->A round-trip (stride 76 -> conflict-free).
// ---------------------------------------------------------------------------
__global__ __launch_bounds__(64) void attn_kernel(
    const bf16_t* __restrict__ Q, const bf16_t* __restrict__ K,
    const bf16_t* __restrict__ Vt, float* __restrict__ O)
{
    __shared__ bf16_t Ps[16][76];

    const int lane = threadIdx.x;
    const int quad = lane >> 4, l16 = lane & 15;

    // block -> strip id, balanced + long-first
    const int z = blockIdx.x, rr = z >> 8, c = z & 255;
    const int sid = (rr == 0) ? 1023 - c : (rr == 1) ? 512 + c
                  : (rr == 2) ? 511 - c  : c;
    const int b = sid & 7, j = sid >> 3;          // j = q-strip index 0..127
    const size_t base = (size_t)b * TT * HSZ;
    const int ntile = (j >> 2) + 1, jm = j & 3;

    const bf16_t* qp = Q + base + (size_t)(j * 16 + l16) * HSZ + quad * 8;
    bf16x8 qf0 = *(const bf16x8*)qp;
    bf16x8 qf1 = *(const bf16x8*)(qp + 32);

    f32x4 o[4];
    #pragma unroll
    for (int dt = 0; dt < 4; ++dt) o[dt] = (f32x4){0.f, 0.f, 0.f, 0.f};
    float m_run[4], l_run[4];
    #pragma unroll
    for (int i = 0; i < 4; ++i) { m_run[i] = -INFINITY; l_run[i] = 0.f; }

    bf16x8 kbuf[2][8];
    #pragma unroll
    for (int n = 0; n < 4; ++n) {
        const bf16_t* kp = K + base + (size_t)(n * 16 + l16) * HSZ + quad * 8;
        kbuf[0][2 * n]     = *(const bf16x8*)kp;
        kbuf[0][2 * n + 1] = *(const bf16x8*)(kp + 32);
    }

    for (int kt = 0; kt < ntile; ++kt) {
        const int cur = kt & 1;
        if (kt + 1 < ntile) {   // prefetch next K tile into the other buffer
            #pragma unroll
            for (int n = 0; n < 4; ++n) {
                const bf16_t* kp = K + base
                    + (size_t)((kt + 1) * 64 + n * 16 + l16) * HSZ + quad * 8;
                kbuf[cur ^ 1][2 * n]     = *(const bf16x8*)kp;
                kbuf[cur ^ 1][2 * n + 1] = *(const bf16x8*)(kp + 32);
            }
        }
        const bool last = (kt == ntile - 1);
        const int nv = last ? jm + 1 : 4;
        const int ksm = (nv > 2) ? 2 : 1;

        // Vt frags for this tile (issued early, used at PV)
        bf16x8 vf[8];
        #pragma unroll
        for (int dt = 0; dt < 4; ++dt) {
            const bf16_t* vp = Vt + ((size_t)b * 64 + dt * 16 + l16) * TT
                                  + kt * 64 + quad * 8;
            vf[dt * 2] = *(const bf16x8*)vp;
            if (ksm == 2) vf[dt * 2 + 1] = *(const bf16x8*)(vp + 32);
        }

        // ---- S = Q K^T ----
        f32x4 sc[4];
        #pragma unroll
        for (int n = 0; n < 4; ++n) {
            if (n < nv) {
                f32x4 a = (f32x4){0.f, 0.f, 0.f, 0.f};
                a = MFMA16(qf0, kbuf[cur][2 * n], a);
                a = MFMA16(qf1, kbuf[cur][2 * n + 1], a);
                sc[n] = a;
            }
        }

        // ---- scale + causal mask + row max ----
        float mx[4];
        #pragma unroll
        for (int i = 0; i < 4; ++i) mx[i] = -INFINITY;
        #pragma unroll
        for (int n = 0; n < 4; ++n) {
            if (n < nv) {
                #pragma unroll
                for (int reg = 0; reg < 4; ++reg) {
                    float s = sc[n][reg] * 0.125f;
                    if (last && n == jm && l16 > quad * 4 + reg) s = -INFINITY;
                    sc[n][reg] = s;
                    mx[reg] = fmaxf(mx[reg], s);
                }
            }
        }
        #pragma unroll
        for (int reg = 0; reg < 4; ++reg) {
            float v = mx[reg];
            v = fmaxf(v, __shfl_xor(v, 1)); v = fmaxf(v, __shfl_xor(v, 2));
            v = fmaxf(v, __shfl_xor(v, 4)); v = fmaxf(v, __shfl_xor(v, 8));
            mx[reg] = v;
        }

        // ---- online softmax ----
        float alpha[4], ls[4];
        #pragma unroll
        for (int reg = 0; reg < 4; ++reg) {
            float m_new = fmaxf(m_run[reg], mx[reg]);
            alpha[reg] = __expf(m_run[reg] - m_new);
            m_run[reg] = m_new;
            ls[reg] = 0.f;
        }
        #pragma unroll
        for (int n = 0; n < 4; ++n) {
            if (n < nv) {
                #pragma unroll
                for (int reg = 0; reg < 4; ++reg) {
                    float p = __expf(sc[n][reg] - m_run[reg]);
                    sc[n][reg] = p;
                    ls[reg] += p;
                }
            }
        }
        #pragma unroll
        for (int reg = 0; reg < 4; ++reg) {
            float v = ls[reg];
            v += __shfl_xor(v, 1); v += __shfl_xor(v, 2);
            v += __shfl_xor(v, 4); v += __shfl_xor(v, 8);
            l_run[reg] = l_run[reg] * alpha[reg] + v;
        }
        #pragma unroll
        for (int dt = 0; dt < 4; ++dt) {
            #pragma unroll
            for (int reg = 0; reg < 4; ++reg) o[dt][reg] *= alpha[reg];
        }

        // ---- P: C-layout -> LDS -> A-layout (same-wave, in-order DS) ----
        #pragma unroll
        for (int n = 0; n < 4; ++n) {
            #pragma unroll
            for (int reg = 0; reg < 4; ++reg) {
                float p = (n < nv) ? sc[n][reg] : 0.f;
                Ps[quad * 4 + reg][n * 16 + l16] = (bf16_t)p;
            }
        }
        bf16x8 pf0 = *(const bf16x8*)&Ps[l16][quad * 8];
        bf16x8 pf1 = *(const bf16x8*)&Ps[l16][32 + quad * 8];

        // ---- O += P V ----
        #pragma unroll
        for (int dt = 0; dt < 4; ++dt) {
            o[dt] = MFMA16(pf0, vf[dt * 2], o[dt]);
            if (ksm == 2) o[dt] = MFMA16(pf1, vf[dt * 2 + 1], o[dt]);
        }
    }

    // ---- epilogue ----
    float linv[4];
    #pragma unroll
    for (int reg = 0; reg < 4; ++reg) linv[reg] = 1.f / l_run[reg];
    #pragma unroll
    for (int dt = 0; dt < 4; ++dt) {
        #pragma unroll
        for (int reg = 0; reg < 4; ++reg) {
            size_t t = (size_t)(j * 16 + quad * 4 + reg);
            O[base + t * HSZ + dt * 16 + l16] = o[dt][reg] * linv[reg];
        }
    }
}

// ---------------------------------------------------------------------------
extern "C" void kernel_launch(void* const* d_in, const int* in_sizes, int n_in,
                              void* d_out, int out_size, void* d_ws, size_t ws_size,
                              hipStream_t stream) {
    const float* ctx = (const float*)d_in[0];
    const float* Wq  = (const float*)d_in[1];
    const float* Wk  = (const float*)d_in[2];
    const float* Wv  = (const float*)d_in[3];
    float* out = (float*)d_out;

    const size_t NQ = (size_t)BB * TT * HSZ;   // 1,048,576
    bf16_t* Qw = (bf16_t*)d_ws;
    bf16_t* Kw = Qw + NQ;
    bf16_t* Vtw = Kw + NQ;                     // transposed [B][HS][T]
    bf16_t* Wt = Vtw + NQ;                     // [3][64][1024]

    wt_convert<<<768, 256, 0, stream>>>(Wq, Wk, Wv, Wt);
    qkv_proj<<<256, 256, 0, stream>>>(ctx, Wt, Qw, Kw, Vtw);
    attn_kernel<<<1024, 64, 0, stream>>>(Qw, Kw, Vtw, out);
}